// Round 1
// baseline (1487.494 us; speedup 1.0000x reference)
//
#include <hip/hip_runtime.h>

// Problem constants (from reference header)
constexpr int B  = 16;
constexpr int LT = 512;
constexpr int D  = 1024;
constexpr int N  = 4096;
constexpr int H  = 16;
constexpr int DH = D / H;       // 64
constexpr int LMAX = N / B;     // 256
constexpr float LN_EPS = 1e-5f;

// ---------------------------------------------------------------------------
// prep: counts = bincount(sb); starts = exclusive cumsum; pos[i] = i - starts[sb[i]]
// lists[b][slot] = pos[i] for each token i of batch b (order-free, used for segment sum)
__global__ void prep_kernel(const int* __restrict__ sb, int* __restrict__ counts,
                            int* __restrict__ starts, int* __restrict__ pos,
                            int* __restrict__ lists) {
    __shared__ int s_counts[B], s_starts[B], s_slot[B];
    int t = threadIdx.x;
    if (t < B) { s_counts[t] = 0; s_slot[t] = 0; }
    __syncthreads();
    for (int i = t; i < N; i += 256) atomicAdd(&s_counts[sb[i]], 1);
    __syncthreads();
    if (t == 0) {
        int run = 0;
        for (int b = 0; b < B; b++) { s_starts[b] = run; run += s_counts[b]; }
    }
    __syncthreads();
    if (t < B) { counts[t] = s_counts[t]; starts[t] = s_starts[t]; }
    for (int i = t; i < N; i += 256) {
        int b = sb[i];
        int p = i - s_starts[b];
        pos[i] = p;
        int slot = atomicAdd(&s_slot[b], 1);
        lists[b * LMAX + slot] = p;
    }
}

// ---------------------------------------------------------------------------
// scatter: padded[sb[i], pos[i], :] = struct_token[i, :]
__global__ void scatter_kernel(const float* __restrict__ st, const int* __restrict__ sb,
                               const int* __restrict__ pos, float* __restrict__ padded) {
    int i = blockIdx.x;
    int b = sb[i], p = pos[i];
    int d = threadIdx.x * 4;
    *(float4*)&padded[((size_t)(b * LMAX + p)) * D + d] =
        *(const float4*)&st[(size_t)i * D + d];
}

// ---------------------------------------------------------------------------
// GEMM: C[M,Nn] = A[M,K] @ W[Nn,K]^T + bias   (both A and W are K-contiguous)
// 128x128 tile, BK=8, 256 threads, 8x8 outputs/thread. M,Nn % 128 == 0, K % 8 == 0.
template<int BM, int BN, int BK>
__global__ __launch_bounds__(256) void gemm_bt(const float* __restrict__ A,
                                               const float* __restrict__ W,
                                               const float* __restrict__ bias,
                                               float* __restrict__ C,
                                               int M, int Nn, int K) {
    __shared__ float As[BK][BM + 4];
    __shared__ float Bs[BK][BN + 4];
    const int tid = threadIdx.x;
    const int m0 = blockIdx.y * BM;
    const int n0 = blockIdx.x * BN;
    const int tm = (tid >> 4) * 8;       // 0..120
    const int tn = (tid & 15) * 8;       // 0..120
    const int lm = tid >> 1;             // 0..127
    const int lk = (tid & 1) * 4;        // 0 or 4

    float acc[8][8] = {};

    for (int k0 = 0; k0 < K; k0 += BK) {
        __syncthreads();
        float4 a = *(const float4*)&A[(size_t)(m0 + lm) * K + k0 + lk];
        float4 w = *(const float4*)&W[(size_t)(n0 + lm) * K + k0 + lk];
        As[lk + 0][lm] = a.x; As[lk + 1][lm] = a.y; As[lk + 2][lm] = a.z; As[lk + 3][lm] = a.w;
        Bs[lk + 0][lm] = w.x; Bs[lk + 1][lm] = w.y; Bs[lk + 2][lm] = w.z; Bs[lk + 3][lm] = w.w;
        __syncthreads();
#pragma unroll
        for (int kk = 0; kk < BK; kk++) {
            float av[8], bv[8];
#pragma unroll
            for (int i = 0; i < 8; i++) av[i] = As[kk][tm + i];
#pragma unroll
            for (int j = 0; j < 8; j++) bv[j] = Bs[kk][tn + j];
#pragma unroll
            for (int i = 0; i < 8; i++)
#pragma unroll
                for (int j = 0; j < 8; j++)
                    acc[i][j] += av[i] * bv[j];
        }
    }

    float bs[8];
#pragma unroll
    for (int j = 0; j < 8; j++) bs[j] = bias[n0 + tn + j];
#pragma unroll
    for (int i = 0; i < 8; i++) {
        size_t off = (size_t)(m0 + tm + i) * Nn + n0 + tn;
        float4 o;
        o.x = acc[i][0] + bs[0]; o.y = acc[i][1] + bs[1];
        o.z = acc[i][2] + bs[2]; o.w = acc[i][3] + bs[3];
        *(float4*)&C[off] = o;
        o.x = acc[i][4] + bs[4]; o.y = acc[i][5] + bs[5];
        o.z = acc[i][6] + bs[6]; o.w = acc[i][7] + bs[7];
        *(float4*)&C[off + 4] = o;
    }
}

// ---------------------------------------------------------------------------
// Attention: one block per (b, h, 8 q-rows). 4 waves, 2 q-rows per wave.
// Two-pass: scores (K tiles staged in LDS) -> softmax (P in LDS) -> ctx (V tiles staged).
__global__ __launch_bounds__(256) void attn_kernel(const float* __restrict__ q,
                                                   const float* __restrict__ k,
                                                   const float* __restrict__ v,
                                                   float* __restrict__ ctx) {
    __shared__ float Ks[64][65];   // K or V tile, bank-conflict-free on [kk][lane]
    __shared__ float qs[8][64];
    __shared__ float P[8][512];

    const int tid = threadIdx.x;
    const int lane = tid & 63;
    const int wv = tid >> 6;               // wave 0..3
    const int b = blockIdx.z, h = blockIdx.y;
    const int qi0 = blockIdx.x * 8 + wv * 2;

    const size_t qbase = ((size_t)(b * LMAX + qi0)) * D + h * DH;
    qs[wv * 2 + 0][lane] = q[qbase + lane];
    qs[wv * 2 + 1][lane] = q[qbase + D + lane];

    const size_t kvbase = (size_t)b * LT * D + h * DH;
    const int cc = (tid & 15) * 4;   // 0..60
    const int rr0 = tid >> 4;        // 0..15

    float sc0[8], sc1[8];
    const float scale = 0.125f;      // 1/sqrt(64)

    for (int tile = 0; tile < 8; tile++) {
        __syncthreads();
        int t0 = tile * 64;
#pragma unroll
        for (int r = 0; r < 4; r++) {
            int row = rr0 + r * 16;
            const float4 kv = *(const float4*)&k[kvbase + (size_t)(t0 + row) * D + cc];
            Ks[row][cc] = kv.x; Ks[row][cc + 1] = kv.y;
            Ks[row][cc + 2] = kv.z; Ks[row][cc + 3] = kv.w;
        }
        __syncthreads();
        float s0 = 0.f, s1 = 0.f;
#pragma unroll
        for (int d = 0; d < 64; d++) {
            float kk_ = Ks[lane][d];
            s0 += kk_ * qs[wv * 2 + 0][d];
            s1 += kk_ * qs[wv * 2 + 1][d];
        }
        sc0[tile] = s0 * scale;
        sc1[tile] = s1 * scale;
    }

    // softmax over 512 keys (each lane holds 8 per row)
    float m0 = sc0[0], m1 = sc1[0];
#pragma unroll
    for (int i = 1; i < 8; i++) { m0 = fmaxf(m0, sc0[i]); m1 = fmaxf(m1, sc1[i]); }
#pragma unroll
    for (int o = 32; o; o >>= 1) {
        m0 = fmaxf(m0, __shfl_xor(m0, o));
        m1 = fmaxf(m1, __shfl_xor(m1, o));
    }
    float e0[8], e1[8], l0 = 0.f, l1 = 0.f;
#pragma unroll
    for (int i = 0; i < 8; i++) {
        e0[i] = __expf(sc0[i] - m0); l0 += e0[i];
        e1[i] = __expf(sc1[i] - m1); l1 += e1[i];
    }
#pragma unroll
    for (int o = 32; o; o >>= 1) { l0 += __shfl_xor(l0, o); l1 += __shfl_xor(l1, o); }
    float inv0 = 1.f / l0, inv1 = 1.f / l1;
#pragma unroll
    for (int i = 0; i < 8; i++) {
        P[wv * 2 + 0][i * 64 + lane] = e0[i] * inv0;
        P[wv * 2 + 1][i * 64 + lane] = e1[i] * inv1;
    }

    // ctx = P @ V
    float a0 = 0.f, a1 = 0.f;
    for (int tile = 0; tile < 8; tile++) {
        __syncthreads();
        int t0 = tile * 64;
#pragma unroll
        for (int r = 0; r < 4; r++) {
            int row = rr0 + r * 16;
            const float4 vv = *(const float4*)&v[kvbase + (size_t)(t0 + row) * D + cc];
            Ks[row][cc] = vv.x; Ks[row][cc + 1] = vv.y;
            Ks[row][cc + 2] = vv.z; Ks[row][cc + 3] = vv.w;
        }
        __syncthreads();
#pragma unroll
        for (int kk = 0; kk < 64; kk++) {
            float vv = Ks[kk][lane];
            a0 += P[wv * 2 + 0][t0 + kk] * vv;
            a1 += P[wv * 2 + 1][t0 + kk] * vv;
        }
    }
    ctx[qbase + lane] = a0;
    ctx[qbase + D + lane] = a1;
}

// ---------------------------------------------------------------------------
// LayerNorm in-place over last dim (D=1024), one block (256 thr) per row.
__global__ __launch_bounds__(256) void ln_kernel(float* __restrict__ f,
                                                 const float* __restrict__ g,
                                                 const float* __restrict__ bb) {
    int row = blockIdx.x;
    float* x = f + (size_t)row * D;
    int t = threadIdx.x;
    float4 val = ((const float4*)x)[t];
    float s = val.x + val.y + val.z + val.w;
    float ss = val.x * val.x + val.y * val.y + val.z * val.z + val.w * val.w;
#pragma unroll
    for (int o = 32; o; o >>= 1) { s += __shfl_xor(s, o); ss += __shfl_xor(ss, o); }
    __shared__ float red[8];
    int wv = t >> 6, ln = t & 63;
    if (ln == 0) { red[wv] = s; red[4 + wv] = ss; }
    __syncthreads();
    s = red[0] + red[1] + red[2] + red[3];
    ss = red[4] + red[5] + red[6] + red[7];
    float mu = s * (1.f / D);
    float var = ss * (1.f / D) - mu * mu;
    float r = rsqrtf(var + LN_EPS);
    float4 gg = ((const float4*)g)[t];
    float4 bv = ((const float4*)bb)[t];
    float4 y;
    y.x = (val.x - mu) * r * gg.x + bv.x;
    y.y = (val.y - mu) * r * gg.y + bv.y;
    y.z = (val.z - mu) * r * gg.z + bv.z;
    y.w = (val.w - mu) * r * gg.w + bv.w;
    ((float4*)x)[t] = y;
}

// ---------------------------------------------------------------------------
// segment mean: out[b,:] = (1/max(cnt,1)) * sum_l f2[b, lists[b][l], :]
__global__ __launch_bounds__(256) void mean_kernel(const float* __restrict__ f2,
                                                   const int* __restrict__ counts,
                                                   const int* __restrict__ lists,
                                                   float* __restrict__ out) {
    int b = blockIdx.x;
    int d4 = threadIdx.x * 4;
    int cnt = counts[b];
    float4 acc = {0.f, 0.f, 0.f, 0.f};
    for (int l = 0; l < cnt; l++) {
        int p = lists[b * LMAX + l];
        const float4 vv = *(const float4*)&f2[((size_t)(b * LMAX + p)) * D + d4];
        acc.x += vv.x; acc.y += vv.y; acc.z += vv.z; acc.w += vv.w;
    }
    float inv = 1.f / (float)max(cnt, 1);
    acc.x *= inv; acc.y *= inv; acc.z *= inv; acc.w *= inv;
    *(float4*)&out[(size_t)b * D + d4] = acc;
}

// ---------------------------------------------------------------------------
extern "C" void kernel_launch(void* const* d_in, const int* in_sizes, int n_in,
                              void* d_out, int out_size, void* d_ws, size_t ws_size,
                              hipStream_t stream) {
    const float* struct_token = (const float*)d_in[0];
    const float* text_token   = (const float*)d_in[1];
    const float* in_proj_w    = (const float*)d_in[2];
    const float* in_proj_b    = (const float*)d_in[3];
    const float* attn_out_w   = (const float*)d_in[4];
    const float* attn_out_b   = (const float*)d_in[5];
    const float* ln_g         = (const float*)d_in[6];
    const float* ln_b         = (const float*)d_in[7];
    const float* proj_w       = (const float*)d_in[8];
    const float* proj_b       = (const float*)d_in[9];
    const int*   sb           = (const int*)d_in[10];
    float* out = (float*)d_out;

    // workspace layout (96 MB floats + ~33 KB ints)
    float* ws = (float*)d_ws;
    float* padded = ws;                                   // B*LMAX*D, later reused as ctx
    float* qbuf   = padded + (size_t)B * LMAX * D;        // B*LMAX*D, later reused as f1
    float* kbuf   = qbuf + (size_t)B * LMAX * D;          // B*LT*D,   later reused as f2
    float* vbuf   = kbuf + (size_t)B * LT * D;            // B*LT*D
    int* pos    = (int*)(vbuf + (size_t)B * LT * D);
    int* counts = pos + N;
    int* starts = counts + B;
    int* lists  = starts + B;                             // B*LMAX

    hipMemsetAsync(padded, 0, (size_t)B * LMAX * D * sizeof(float), stream);
    prep_kernel<<<1, 256, 0, stream>>>(sb, counts, starts, pos, lists);
    scatter_kernel<<<N, 256, 0, stream>>>(struct_token, sb, pos, padded);

    // QKV projections
    gemm_bt<128, 128, 8><<<dim3(D / 128, (B * LMAX) / 128), 256, 0, stream>>>(
        padded, in_proj_w, in_proj_b, qbuf, B * LMAX, D, D);
    gemm_bt<128, 128, 8><<<dim3(D / 128, (B * LT) / 128), 256, 0, stream>>>(
        text_token, in_proj_w + (size_t)D * D, in_proj_b + D, kbuf, B * LT, D, D);
    gemm_bt<128, 128, 8><<<dim3(D / 128, (B * LT) / 128), 256, 0, stream>>>(
        text_token, in_proj_w + 2 * (size_t)D * D, in_proj_b + 2 * D, vbuf, B * LT, D, D);

    // attention -> ctx (reuses padded)
    attn_kernel<<<dim3(LMAX / 8, H, B), 256, 0, stream>>>(qbuf, kbuf, vbuf, padded);

    // attn_out projection -> f1 (reuses qbuf), then LayerNorm in place
    gemm_bt<128, 128, 8><<<dim3(D / 128, (B * LMAX) / 128), 256, 0, stream>>>(
        padded, attn_out_w, attn_out_b, qbuf, B * LMAX, D, D);
    ln_kernel<<<B * LMAX, 256, 0, stream>>>(qbuf, ln_g, ln_b);

    // final projection -> f2 (reuses kbuf)
    gemm_bt<128, 128, 8><<<dim3(D / 128, (B * LMAX) / 128), 256, 0, stream>>>(
        qbuf, proj_w, proj_b, kbuf, B * LMAX, D, D);

    // gather + segment mean
    mean_kernel<<<B, 256, 0, stream>>>(kbuf, counts, lists, out);
}

// Round 2
// 780.499 us; speedup vs baseline: 1.9058x; 1.9058x over previous
//
#include <hip/hip_runtime.h>

// Problem constants
constexpr int B  = 16;
constexpr int LT = 512;
constexpr int D  = 1024;
constexpr int N  = 4096;
constexpr int H  = 16;
constexpr int DH = D / H;       // 64
constexpr int LMAX = N / B;     // 256
constexpr float LN_EPS = 1e-5f;

typedef short  s16x8 __attribute__((ext_vector_type(8)));
typedef float  f32x4 __attribute__((ext_vector_type(4)));

__device__ __forceinline__ unsigned short f2bf(float x) {
    unsigned int u = __float_as_uint(x);
    unsigned int r = (u + 0x7fffu + ((u >> 16) & 1u)) >> 16;   // RNE
    return (unsigned short)r;
}

// async 16B global->LDS (wave-uniform LDS base + lane*16)
__device__ __forceinline__ void load_lds16(const void* g, void* l) {
    __builtin_amdgcn_global_load_lds(
        (const __attribute__((address_space(1))) unsigned int*)g,
        (__attribute__((address_space(3))) unsigned int*)l, 16, 0, 0);
}

// ---------------------------------------------------------------------------
// prep: counts/starts/pos + per-batch slot lists
__global__ void prep_kernel(const int* __restrict__ sb, int* __restrict__ counts,
                            int* __restrict__ starts, int* __restrict__ pos,
                            int* __restrict__ lists) {
    __shared__ int s_counts[B], s_starts[B], s_slot[B];
    int t = threadIdx.x;
    if (t < B) { s_counts[t] = 0; s_slot[t] = 0; }
    __syncthreads();
    for (int i = t; i < N; i += 256) atomicAdd(&s_counts[sb[i]], 1);
    __syncthreads();
    if (t == 0) {
        int run = 0;
        for (int b = 0; b < B; b++) { s_starts[b] = run; run += s_counts[b]; }
    }
    __syncthreads();
    if (t < B) { counts[t] = s_counts[t]; starts[t] = s_starts[t]; }
    for (int i = t; i < N; i += 256) {
        int b = sb[i];
        int p = i - s_starts[b];
        pos[i] = p;
        int slot = atomicAdd(&s_slot[b], 1);
        lists[b * LMAX + slot] = p;
    }
}

// ---------------------------------------------------------------------------
// scatter fp32 struct tokens into zeroed bf16 padded buffer
__global__ void scatter_kernel(const float* __restrict__ st, const int* __restrict__ sb,
                               const int* __restrict__ pos, unsigned short* __restrict__ padded) {
    int i = blockIdx.x;
    int b = sb[i], p = pos[i];
    int d = threadIdx.x * 4;
    float4 v = *(const float4*)&st[(size_t)i * D + d];
    ushort4 o;
    o.x = f2bf(v.x); o.y = f2bf(v.y); o.z = f2bf(v.z); o.w = f2bf(v.w);
    *(ushort4*)&padded[((size_t)(b * LMAX + p)) * D + d] = o;
}

// fp32 -> bf16 cast, 8 elems/thread. n must be a multiple of 8.
__global__ __launch_bounds__(256) void cast_kernel(const float* __restrict__ x,
                                                   unsigned short* __restrict__ y, int n) {
    int i = (blockIdx.x * 256 + threadIdx.x) * 8;
    if (i >= n) return;
    float4 a = *(const float4*)&x[i];
    float4 b = *(const float4*)&x[i + 4];
    ushort4 o1, o2;
    o1.x = f2bf(a.x); o1.y = f2bf(a.y); o1.z = f2bf(a.z); o1.w = f2bf(a.w);
    o2.x = f2bf(b.x); o2.y = f2bf(b.y); o2.z = f2bf(b.z); o2.w = f2bf(b.w);
    *(ushort4*)&y[i] = o1;
    *(ushort4*)&y[i + 4] = o2;
}

// ---------------------------------------------------------------------------
// bf16 MFMA GEMM (m97 pattern): C[M,Nn] = A[M,K] @ W[Nn,K]^T + bias, C fp32.
// 128x128 tile, BK=32, 256 thr = 4 waves (2x2 of 64x64), 16x16x32 MFMA.
// M,Nn % 128 == 0, K % 32 == 0. A,W bf16 bit patterns in ushort.
__global__ __launch_bounds__(256) void gemm_mfma(const unsigned short* __restrict__ A,
                                                 const unsigned short* __restrict__ W,
                                                 const float* __restrict__ bias,
                                                 float* __restrict__ C,
                                                 int M, int Nn, int K) {
    __shared__ __align__(16) unsigned short As[128 * 32];
    __shared__ __align__(16) unsigned short Bs[128 * 32];
    const int tid  = threadIdx.x;
    const int lane = tid & 63;
    const int wave = tid >> 6;
    const int m0 = blockIdx.y * 128, n0 = blockIdx.x * 128;
    const int wm = (wave >> 1) * 64, wn = (wave & 1) * 64;

    // staging: thread t owns the 16B chunk at LDS elem offset t*8 (row t/4, chunk t%4)
    const int srow = tid >> 2;
    const int scol = (tid & 3) * 8;
    const unsigned short* Ag = A + (size_t)(m0 + srow) * K + scol;
    const unsigned short* Wg = W + (size_t)(n0 + srow) * K + scol;
    unsigned short* Asl = As + tid * 8;
    unsigned short* Bsl = Bs + tid * 8;

    // fragment indices: A[m=lane&15][k=(lane>>4)*8+j], same for B with n=lane&15
    const int fm = lane & 15;
    const int fk = (lane >> 4) * 8;

    f32x4 acc[4][4];
#pragma unroll
    for (int i = 0; i < 4; i++)
#pragma unroll
        for (int j = 0; j < 4; j++) acc[i][j] = (f32x4){0.f, 0.f, 0.f, 0.f};

    for (int k0 = 0; k0 < K; k0 += 32) {
        __syncthreads();
        load_lds16(Ag + k0, Asl);
        load_lds16(Ag + (size_t)64 * K + k0, Asl + 64 * 32);
        load_lds16(Wg + k0, Bsl);
        load_lds16(Wg + (size_t)64 * K + k0, Bsl + 64 * 32);
        __syncthreads();   // compiler drains vmcnt(0) before s_barrier

        s16x8 af[4], bf[4];
#pragma unroll
        for (int i = 0; i < 4; i++) {
            af[i] = *(const s16x8*)&As[(wm + i * 16 + fm) * 32 + fk];
            bf[i] = *(const s16x8*)&Bs[(wn + i * 16 + fm) * 32 + fk];
        }
#pragma unroll
        for (int i = 0; i < 4; i++)
#pragma unroll
            for (int j = 0; j < 4; j++)
                acc[i][j] = __builtin_amdgcn_mfma_f32_16x16x32_bf16(af[i], bf[j], acc[i][j], 0, 0, 0);
    }

    // C/D layout (m89-verified): col = lane&15, row = (lane>>4)*4 + reg
    const int fr = (lane >> 4) * 4;
#pragma unroll
    for (int j = 0; j < 4; j++) {
        int col = n0 + wn + j * 16 + fm;
        float bv = bias[col];
#pragma unroll
        for (int i = 0; i < 4; i++) {
            size_t rbase = (size_t)(m0 + wm + i * 16 + fr) * Nn + col;
#pragma unroll
            for (int r = 0; r < 4; r++)
                C[rbase + (size_t)r * Nn] = acc[i][j][r] + bv;
        }
    }
}

// ---------------------------------------------------------------------------
// Attention (unchanged fp32 math from round 1), ctx stored as bf16.
__global__ __launch_bounds__(256) void attn_kernel(const float* __restrict__ q,
                                                   const float* __restrict__ k,
                                                   const float* __restrict__ v,
                                                   unsigned short* __restrict__ ctx) {
    __shared__ float Ks[64][65];
    __shared__ float qs[8][64];
    __shared__ float P[8][512];

    const int tid = threadIdx.x;
    const int lane = tid & 63;
    const int wv = tid >> 6;
    const int b = blockIdx.z, h = blockIdx.y;
    const int qi0 = blockIdx.x * 8 + wv * 2;

    const size_t qbase = ((size_t)(b * LMAX + qi0)) * D + h * DH;
    qs[wv * 2 + 0][lane] = q[qbase + lane];
    qs[wv * 2 + 1][lane] = q[qbase + D + lane];

    const size_t kvbase = (size_t)b * LT * D + h * DH;
    const int cc = (tid & 15) * 4;
    const int rr0 = tid >> 4;

    float sc0[8], sc1[8];
    const float scale = 0.125f;

    for (int tile = 0; tile < 8; tile++) {
        __syncthreads();
        int t0 = tile * 64;
#pragma unroll
        for (int r = 0; r < 4; r++) {
            int row = rr0 + r * 16;
            const float4 kv = *(const float4*)&k[kvbase + (size_t)(t0 + row) * D + cc];
            Ks[row][cc] = kv.x; Ks[row][cc + 1] = kv.y;
            Ks[row][cc + 2] = kv.z; Ks[row][cc + 3] = kv.w;
        }
        __syncthreads();
        float s0 = 0.f, s1 = 0.f;
#pragma unroll
        for (int d = 0; d < 64; d++) {
            float kk_ = Ks[lane][d];
            s0 += kk_ * qs[wv * 2 + 0][d];
            s1 += kk_ * qs[wv * 2 + 1][d];
        }
        sc0[tile] = s0 * scale;
        sc1[tile] = s1 * scale;
    }

    float m0 = sc0[0], m1 = sc1[0];
#pragma unroll
    for (int i = 1; i < 8; i++) { m0 = fmaxf(m0, sc0[i]); m1 = fmaxf(m1, sc1[i]); }
#pragma unroll
    for (int o = 32; o; o >>= 1) {
        m0 = fmaxf(m0, __shfl_xor(m0, o));
        m1 = fmaxf(m1, __shfl_xor(m1, o));
    }
    float e0[8], e1[8], l0 = 0.f, l1 = 0.f;
#pragma unroll
    for (int i = 0; i < 8; i++) {
        e0[i] = __expf(sc0[i] - m0); l0 += e0[i];
        e1[i] = __expf(sc1[i] - m1); l1 += e1[i];
    }
#pragma unroll
    for (int o = 32; o; o >>= 1) { l0 += __shfl_xor(l0, o); l1 += __shfl_xor(l1, o); }
    float inv0 = 1.f / l0, inv1 = 1.f / l1;
#pragma unroll
    for (int i = 0; i < 8; i++) {
        P[wv * 2 + 0][i * 64 + lane] = e0[i] * inv0;
        P[wv * 2 + 1][i * 64 + lane] = e1[i] * inv1;
    }

    float a0 = 0.f, a1 = 0.f;
    for (int tile = 0; tile < 8; tile++) {
        __syncthreads();
        int t0 = tile * 64;
#pragma unroll
        for (int r = 0; r < 4; r++) {
            int row = rr0 + r * 16;
            const float4 vv = *(const float4*)&v[kvbase + (size_t)(t0 + row) * D + cc];
            Ks[row][cc] = vv.x; Ks[row][cc + 1] = vv.y;
            Ks[row][cc + 2] = vv.z; Ks[row][cc + 3] = vv.w;
        }
        __syncthreads();
#pragma unroll
        for (int kk = 0; kk < 64; kk++) {
            float vv = Ks[kk][lane];
            a0 += P[wv * 2 + 0][t0 + kk] * vv;
            a1 += P[wv * 2 + 1][t0 + kk] * vv;
        }
    }
    ctx[qbase + lane]     = f2bf(a0);
    ctx[qbase + D + lane] = f2bf(a1);
}

// ---------------------------------------------------------------------------
// LayerNorm: reads fp32 row, writes bf16 row. One block (256 thr) per row.
__global__ __launch_bounds__(256) void ln_kernel(const float* __restrict__ f,
                                                 unsigned short* __restrict__ y,
                                                 const float* __restrict__ g,
                                                 const float* __restrict__ bb) {
    int row = blockIdx.x;
    const float* x = f + (size_t)row * D;
    int t = threadIdx.x;
    float4 val = ((const float4*)x)[t];
    float s = val.x + val.y + val.z + val.w;
    float ss = val.x * val.x + val.y * val.y + val.z * val.z + val.w * val.w;
#pragma unroll
    for (int o = 32; o; o >>= 1) { s += __shfl_xor(s, o); ss += __shfl_xor(ss, o); }
    __shared__ float red[8];
    int wv = t >> 6, ln = t & 63;
    if (ln == 0) { red[wv] = s; red[4 + wv] = ss; }
    __syncthreads();
    s = red[0] + red[1] + red[2] + red[3];
    ss = red[4] + red[5] + red[6] + red[7];
    float mu = s * (1.f / D);
    float var = ss * (1.f / D) - mu * mu;
    float r = rsqrtf(var + LN_EPS);
    float4 gg = ((const float4*)g)[t];
    float4 bv = ((const float4*)bb)[t];
    ushort4 o;
    o.x = f2bf((val.x - mu) * r * gg.x + bv.x);
    o.y = f2bf((val.y - mu) * r * gg.y + bv.y);
    o.z = f2bf((val.z - mu) * r * gg.z + bv.z);
    o.w = f2bf((val.w - mu) * r * gg.w + bv.w);
    *(ushort4*)&y[(size_t)row * D + t * 4] = o;
}

// ---------------------------------------------------------------------------
__global__ __launch_bounds__(256) void mean_kernel(const float* __restrict__ f2,
                                                   const int* __restrict__ counts,
                                                   const int* __restrict__ lists,
                                                   float* __restrict__ out) {
    int b = blockIdx.x;
    int d4 = threadIdx.x * 4;
    int cnt = counts[b];
    float4 acc = {0.f, 0.f, 0.f, 0.f};
    for (int l = 0; l < cnt; l++) {
        int p = lists[b * LMAX + l];
        const float4 vv = *(const float4*)&f2[((size_t)(b * LMAX + p)) * D + d4];
        acc.x += vv.x; acc.y += vv.y; acc.z += vv.z; acc.w += vv.w;
    }
    float inv = 1.f / (float)max(cnt, 1);
    acc.x *= inv; acc.y *= inv; acc.z *= inv; acc.w *= inv;
    *(float4*)&out[(size_t)b * D + d4] = acc;
}

// ---------------------------------------------------------------------------
extern "C" void kernel_launch(void* const* d_in, const int* in_sizes, int n_in,
                              void* d_out, int out_size, void* d_ws, size_t ws_size,
                              hipStream_t stream) {
    const float* struct_token = (const float*)d_in[0];
    const float* text_token   = (const float*)d_in[1];
    const float* in_proj_w    = (const float*)d_in[2];
    const float* in_proj_b    = (const float*)d_in[3];
    const float* attn_out_w   = (const float*)d_in[4];
    const float* attn_out_b   = (const float*)d_in[5];
    const float* ln_g         = (const float*)d_in[6];
    const float* ln_b         = (const float*)d_in[7];
    const float* proj_w       = (const float*)d_in[8];
    const float* proj_b       = (const float*)d_in[9];
    const int*   sb           = (const int*)d_in[10];
    float* out = (float*)d_out;

    const size_t MQ = (size_t)B * LMAX;      // 4096
    const size_t MKV = (size_t)B * LT;       // 8192

    // workspace carve (bytes), all offsets 256B-aligned
    char* p = (char*)d_ws;
    unsigned short* padded_b = (unsigned short*)p;  p += MQ * D * 2;         // 8 MB
    unsigned short* text_b   = (unsigned short*)p;  p += MKV * D * 2;        // 16 MB
    unsigned short* wqkv_b   = (unsigned short*)p;  p += (size_t)3 * D * D * 2; // 6 MB
    unsigned short* wattn_b  = (unsigned short*)p;  p += (size_t)D * D * 2;  // 2 MB
    unsigned short* wproj_b  = (unsigned short*)p;  p += (size_t)D * D * 2;  // 2 MB
    unsigned short* ctx_b    = (unsigned short*)p;  p += MQ * D * 2;         // 8 MB
    unsigned short* f1b_b    = (unsigned short*)p;  p += MQ * D * 2;         // 8 MB
    float* qbuf = (float*)p;  p += MQ * D * 4;                                // 16 MB
    float* kbuf = (float*)p;  p += MKV * D * 4;                               // 32 MB
    float* vbuf = (float*)p;  p += MKV * D * 4;                               // 32 MB
    float* f1 = vbuf;          // reuse (vbuf dead after attention)
    float* f2 = kbuf;          // reuse (kbuf dead after attention)
    int* pos    = (int*)p;  p += N * 4;
    int* counts = (int*)p;  p += B * 4;
    int* starts = (int*)p;  p += B * 4;
    int* lists  = (int*)p;  p += B * LMAX * 4;

    hipMemsetAsync(padded_b, 0, MQ * D * 2, stream);
    prep_kernel<<<1, 256, 0, stream>>>(sb, counts, starts, pos, lists);
    scatter_kernel<<<N, 256, 0, stream>>>(struct_token, sb, pos, padded_b);

    // bf16 casts
    cast_kernel<<<(int)(MKV * D / 8 / 256), 256, 0, stream>>>(text_token, text_b, (int)(MKV * D));
    cast_kernel<<<(int)(3 * D * D / 8 / 256), 256, 0, stream>>>(in_proj_w, wqkv_b, 3 * D * D);
    cast_kernel<<<(int)(D * D / 8 / 256), 256, 0, stream>>>(attn_out_w, wattn_b, D * D);
    cast_kernel<<<(int)(D * D / 8 / 256), 256, 0, stream>>>(proj_w, wproj_b, D * D);

    // QKV projections (bf16 MFMA, fp32 out)
    gemm_mfma<<<dim3(D / 128, MQ / 128), 256, 0, stream>>>(
        padded_b, wqkv_b, in_proj_b, qbuf, (int)MQ, D, D);
    gemm_mfma<<<dim3(D / 128, MKV / 128), 256, 0, stream>>>(
        text_b, wqkv_b + (size_t)D * D, in_proj_b + D, kbuf, (int)MKV, D, D);
    gemm_mfma<<<dim3(D / 128, MKV / 128), 256, 0, stream>>>(
        text_b, wqkv_b + 2 * (size_t)D * D, in_proj_b + 2 * D, vbuf, (int)MKV, D, D);

    // attention -> ctx (bf16)
    attn_kernel<<<dim3(LMAX / 8, H, B), 256, 0, stream>>>(qbuf, kbuf, vbuf, ctx_b);

    // attn_out projection -> f1 (fp32, reuses vbuf), LN -> f1b (bf16)
    gemm_mfma<<<dim3(D / 128, MQ / 128), 256, 0, stream>>>(
        ctx_b, wattn_b, attn_out_b, f1, (int)MQ, D, D);
    ln_kernel<<<(int)MQ, 256, 0, stream>>>(f1, f1b_b, ln_g, ln_b);

    // final projection -> f2 (fp32, reuses kbuf)
    gemm_mfma<<<dim3(D / 128, MQ / 128), 256, 0, stream>>>(
        f1b_b, wproj_b, proj_b, f2, (int)MQ, D, D);

    mean_kernel<<<B, 256, 0, stream>>>(f2, counts, lists, out);
}

// Round 3
// 341.642 us; speedup vs baseline: 4.3540x; 2.2846x over previous
//
#include <hip/hip_runtime.h>

// Problem constants
constexpr int B  = 16;
constexpr int LT = 512;
constexpr int D  = 1024;
constexpr int N  = 4096;
constexpr int H  = 16;
constexpr int DH = D / H;       // 64
constexpr int LMAX = N / B;     // 256
constexpr float LN_EPS = 1e-5f;

typedef short  s16x8 __attribute__((ext_vector_type(8)));
typedef float  f32x4 __attribute__((ext_vector_type(4)));

__device__ __forceinline__ unsigned short f2bf(float x) {
    unsigned int u = __float_as_uint(x);
    unsigned int r = (u + 0x7fffu + ((u >> 16) & 1u)) >> 16;   // RNE
    return (unsigned short)r;
}

__device__ __forceinline__ void load_lds16(const void* g, void* l) {
    __builtin_amdgcn_global_load_lds(
        (const __attribute__((address_space(1))) unsigned int*)g,
        (__attribute__((address_space(3))) unsigned int*)l, 16, 0, 0);
}

// ---------------------------------------------------------------------------
__global__ void prep_kernel(const int* __restrict__ sb, int* __restrict__ counts,
                            int* __restrict__ starts, int* __restrict__ pos,
                            int* __restrict__ lists) {
    __shared__ int s_counts[B], s_starts[B], s_slot[B];
    int t = threadIdx.x;
    if (t < B) { s_counts[t] = 0; s_slot[t] = 0; }
    __syncthreads();
    for (int i = t; i < N; i += 256) atomicAdd(&s_counts[sb[i]], 1);
    __syncthreads();
    if (t == 0) {
        int run = 0;
        for (int b = 0; b < B; b++) { s_starts[b] = run; run += s_counts[b]; }
    }
    __syncthreads();
    if (t < B) { counts[t] = s_counts[t]; starts[t] = s_starts[t]; }
    for (int i = t; i < N; i += 256) {
        int b = sb[i];
        int p = i - s_starts[b];
        pos[i] = p;
        int slot = atomicAdd(&s_slot[b], 1);
        lists[b * LMAX + slot] = p;
    }
}

// ---------------------------------------------------------------------------
__global__ void scatter_kernel(const float* __restrict__ st, const int* __restrict__ sb,
                               const int* __restrict__ pos, unsigned short* __restrict__ padded) {
    int i = blockIdx.x;
    int b = sb[i], p = pos[i];
    int d = threadIdx.x * 4;
    float4 v = *(const float4*)&st[(size_t)i * D + d];
    ushort4 o;
    o.x = f2bf(v.x); o.y = f2bf(v.y); o.z = f2bf(v.z); o.w = f2bf(v.w);
    *(ushort4*)&padded[((size_t)(b * LMAX + p)) * D + d] = o;
}

__global__ __launch_bounds__(256) void cast_kernel(const float* __restrict__ x,
                                                   unsigned short* __restrict__ y, int n) {
    int i = (blockIdx.x * 256 + threadIdx.x) * 8;
    if (i >= n) return;
    float4 a = *(const float4*)&x[i];
    float4 b = *(const float4*)&x[i + 4];
    ushort4 o1, o2;
    o1.x = f2bf(a.x); o1.y = f2bf(a.y); o1.z = f2bf(a.z); o1.w = f2bf(a.w);
    o2.x = f2bf(b.x); o2.y = f2bf(b.y); o2.z = f2bf(b.z); o2.w = f2bf(b.w);
    *(ushort4*)&y[i] = o1;
    *(ushort4*)&y[i + 4] = o2;
}

// ---------------------------------------------------------------------------
// bf16 MFMA GEMM: C[M,Nn] = A[M,K] @ W[Nn,K]^T + bias.
// OutT in {float, unsigned short(bf16)}. BIAS_ROW: bias indexed by row (m) not col.
template<typename OutT, bool BIAS_ROW>
__global__ __launch_bounds__(256) void gemm_mfma(const unsigned short* __restrict__ A,
                                                 const unsigned short* __restrict__ W,
                                                 const float* __restrict__ bias,
                                                 OutT* __restrict__ C,
                                                 int M, int Nn, int K) {
    __shared__ __align__(16) unsigned short As[128 * 32];
    __shared__ __align__(16) unsigned short Bs[128 * 32];
    const int tid  = threadIdx.x;
    const int lane = tid & 63;
    const int wave = tid >> 6;
    const int m0 = blockIdx.y * 128, n0 = blockIdx.x * 128;
    const int wm = (wave >> 1) * 64, wn = (wave & 1) * 64;

    const int srow = tid >> 2;
    const int scol = (tid & 3) * 8;
    const unsigned short* Ag = A + (size_t)(m0 + srow) * K + scol;
    const unsigned short* Wg = W + (size_t)(n0 + srow) * K + scol;
    unsigned short* Asl = As + tid * 8;
    unsigned short* Bsl = Bs + tid * 8;

    const int fm = lane & 15;
    const int fk = (lane >> 4) * 8;

    f32x4 acc[4][4];
#pragma unroll
    for (int i = 0; i < 4; i++)
#pragma unroll
        for (int j = 0; j < 4; j++) acc[i][j] = (f32x4){0.f, 0.f, 0.f, 0.f};

    for (int k0 = 0; k0 < K; k0 += 32) {
        __syncthreads();
        load_lds16(Ag + k0, Asl);
        load_lds16(Ag + (size_t)64 * K + k0, Asl + 64 * 32);
        load_lds16(Wg + k0, Bsl);
        load_lds16(Wg + (size_t)64 * K + k0, Bsl + 64 * 32);
        __syncthreads();

        s16x8 af[4], bf[4];
#pragma unroll
        for (int i = 0; i < 4; i++) {
            af[i] = *(const s16x8*)&As[(wm + i * 16 + fm) * 32 + fk];
            bf[i] = *(const s16x8*)&Bs[(wn + i * 16 + fm) * 32 + fk];
        }
#pragma unroll
        for (int i = 0; i < 4; i++)
#pragma unroll
            for (int j = 0; j < 4; j++)
                acc[i][j] = __builtin_amdgcn_mfma_f32_16x16x32_bf16(af[i], bf[j], acc[i][j], 0, 0, 0);
    }

    const int fr = (lane >> 4) * 4;
#pragma unroll
    for (int j = 0; j < 4; j++) {
        int col = n0 + wn + j * 16 + fm;
        float bc = BIAS_ROW ? 0.f : bias[col];
#pragma unroll
        for (int i = 0; i < 4; i++) {
            size_t rbase = (size_t)(m0 + wm + i * 16 + fr) * Nn + col;
#pragma unroll
            for (int r = 0; r < 4; r++) {
                float val = acc[i][j][r] + (BIAS_ROW ? bias[m0 + wm + i * 16 + fr + r] : bc);
                if constexpr (sizeof(OutT) == 2)
                    C[rbase + (size_t)r * Nn] = (OutT)f2bf(val);
                else
                    C[rbase + (size_t)r * Nn] = (OutT)val;
            }
        }
    }
}

// ---------------------------------------------------------------------------
// MFMA attention. Block = (b, h, 64 q-rows), 4 waves x 16 q-rows.
// qb [4096][1024], kb [8192][1024], vtb = V^T [1024][8192], ctx [4096][1024], all bf16.
__global__ __launch_bounds__(256) void attn_mfma(const unsigned short* __restrict__ qb,
                                                 const unsigned short* __restrict__ kb,
                                                 const unsigned short* __restrict__ vtb,
                                                 unsigned short* __restrict__ ctx) {
    __shared__ __align__(16) unsigned short KV[128 * 72];      // K chunk [128][72] / V^T chunk [64][136]
    __shared__ __align__(16) unsigned short Ps[4 * 16 * 136];  // per-wave P chunk [16][136]

    const int tid = threadIdx.x;
    const int lane = tid & 63;
    const int wv = tid >> 6;
    const int fm = lane & 15;       // A/B fragment row, C/D col
    const int quad = lane >> 4;     // 0..3
    const int b = blockIdx.z, h = blockIdx.y;
    const int q0 = blockIdx.x * 64 + wv * 16;

    // Q A-fragments (dh=64 -> 2 k-steps), straight from global
    const size_t qrow = (size_t)(b * LMAX + q0 + fm) * D + h * DH;
    const s16x8 aq0 = *(const s16x8*)&qb[qrow + quad * 8];
    const s16x8 aq1 = *(const s16x8*)&qb[qrow + 32 + quad * 8];

    f32x4 sc[32];
#pragma unroll
    for (int t = 0; t < 32; t++) sc[t] = (f32x4){0.f, 0.f, 0.f, 0.f};

    // ---- pass 1: scores (4 chunks of 128 keys) ----
    const size_t kbase = (size_t)(b * LT) * D + h * DH;
    for (int c = 0; c < 4; c++) {
        __syncthreads();
#pragma unroll
        for (int it = 0; it < 4; it++) {
            int e = it * 2048 + tid * 8;
            int row = e >> 6, col = e & 63;
            *(s16x8*)&KV[row * 72 + col] =
                *(const s16x8*)&kb[kbase + (size_t)(c * 128 + row) * D + col];
        }
        __syncthreads();
#pragma unroll
        for (int t = 0; t < 8; t++) {
            s16x8 bk0 = *(const s16x8*)&KV[(t * 16 + fm) * 72 + quad * 8];
            s16x8 bk1 = *(const s16x8*)&KV[(t * 16 + fm) * 72 + 32 + quad * 8];
            f32x4 a = sc[c * 8 + t];
            a = __builtin_amdgcn_mfma_f32_16x16x32_bf16(aq0, bk0, a, 0, 0, 0);
            a = __builtin_amdgcn_mfma_f32_16x16x32_bf16(aq1, bk1, a, 0, 0, 0);
            sc[c * 8 + t] = a;
        }
    }

    // ---- softmax in registers: row q = quad*4+r lives on the 16 lanes of this quad ----
    const float scale = 0.125f;   // 1/sqrt(64)
    float mx[4], l[4], inv[4];
#pragma unroll
    for (int r = 0; r < 4; r++) {
        float m = sc[0][r];
#pragma unroll
        for (int t = 1; t < 32; t++) m = fmaxf(m, sc[t][r]);
        mx[r] = m;
    }
#pragma unroll
    for (int o = 1; o < 16; o <<= 1)
#pragma unroll
        for (int r = 0; r < 4; r++) mx[r] = fmaxf(mx[r], __shfl_xor(mx[r], o));
#pragma unroll
    for (int r = 0; r < 4; r++) l[r] = 0.f;
#pragma unroll
    for (int t = 0; t < 32; t++)
#pragma unroll
        for (int r = 0; r < 4; r++) {
            float e = __expf((sc[t][r] - mx[r]) * scale);
            sc[t][r] = e;
            l[r] += e;
        }
#pragma unroll
    for (int o = 1; o < 16; o <<= 1)
#pragma unroll
        for (int r = 0; r < 4; r++) l[r] += __shfl_xor(l[r], o);
#pragma unroll
    for (int r = 0; r < 4; r++) inv[r] = 1.f / l[r];

    // ---- pass 2: ctx = P @ V via V^T chunks ----
    f32x4 co[4];
#pragma unroll
    for (int n = 0; n < 4; n++) co[n] = (f32x4){0.f, 0.f, 0.f, 0.f};
    unsigned short* Pw = Ps + wv * (16 * 136);
    const size_t vbase = (size_t)(h * DH) * (B * LT) + (size_t)b * LT;

    for (int c = 0; c < 4; c++) {
        __syncthreads();
        // stage V^T chunk [64 d][128 keys], padded stride 136
#pragma unroll
        for (int it = 0; it < 4; it++) {
            int e = it * 2048 + tid * 8;
            int row = e >> 7, col = e & 127;
            *(s16x8*)&KV[row * 136 + col] =
                *(const s16x8*)&vtb[vbase + (size_t)row * (B * LT) + c * 128 + col];
        }
        // write this wave's P chunk (C-layout regs -> [q][key] bf16)
#pragma unroll
        for (int t = 0; t < 8; t++)
#pragma unroll
            for (int r = 0; r < 4; r++)
                Pw[(quad * 4 + r) * 136 + t * 16 + fm] = f2bf(sc[c * 8 + t][r]);
        __syncthreads();
#pragma unroll
        for (int s = 0; s < 4; s++) {
            s16x8 ap = *(const s16x8*)&Pw[fm * 136 + s * 32 + quad * 8];
#pragma unroll
            for (int n = 0; n < 4; n++) {
                s16x8 bv = *(const s16x8*)&KV[(n * 16 + fm) * 136 + s * 32 + quad * 8];
                co[n] = __builtin_amdgcn_mfma_f32_16x16x32_bf16(ap, bv, co[n], 0, 0, 0);
            }
        }
    }

    // ---- store ctx (C-layout), fold in 1/l ----
    const size_t obase = (size_t)(b * LMAX + q0) * D + h * DH;
#pragma unroll
    for (int n = 0; n < 4; n++)
#pragma unroll
        for (int r = 0; r < 4; r++)
            ctx[obase + (size_t)(quad * 4 + r) * D + n * 16 + fm] = f2bf(co[n][r] * inv[r]);
}

// ---------------------------------------------------------------------------
__global__ __launch_bounds__(256) void ln_kernel(const float* __restrict__ f,
                                                 unsigned short* __restrict__ y,
                                                 const float* __restrict__ g,
                                                 const float* __restrict__ bb) {
    int row = blockIdx.x;
    const float* x = f + (size_t)row * D;
    int t = threadIdx.x;
    float4 val = ((const float4*)x)[t];
    float s = val.x + val.y + val.z + val.w;
    float ss = val.x * val.x + val.y * val.y + val.z * val.z + val.w * val.w;
#pragma unroll
    for (int o = 32; o; o >>= 1) { s += __shfl_xor(s, o); ss += __shfl_xor(ss, o); }
    __shared__ float red[8];
    int wv = t >> 6, ln = t & 63;
    if (ln == 0) { red[wv] = s; red[4 + wv] = ss; }
    __syncthreads();
    s = red[0] + red[1] + red[2] + red[3];
    ss = red[4] + red[5] + red[6] + red[7];
    float mu = s * (1.f / D);
    float var = ss * (1.f / D) - mu * mu;
    float r = rsqrtf(var + LN_EPS);
    float4 gg = ((const float4*)g)[t];
    float4 bv = ((const float4*)bb)[t];
    ushort4 o;
    o.x = f2bf((val.x - mu) * r * gg.x + bv.x);
    o.y = f2bf((val.y - mu) * r * gg.y + bv.y);
    o.z = f2bf((val.z - mu) * r * gg.z + bv.z);
    o.w = f2bf((val.w - mu) * r * gg.w + bv.w);
    *(ushort4*)&y[(size_t)row * D + t * 4] = o;
}

// ---------------------------------------------------------------------------
// segment mean, split 8-way over rows; out must be zeroed first.
__global__ __launch_bounds__(256) void mean_kernel(const float* __restrict__ f2,
                                                   const int* __restrict__ counts,
                                                   const int* __restrict__ lists,
                                                   float* __restrict__ out) {
    int b = blockIdx.x;
    int cnt = counts[b];
    int l0 = blockIdx.y * 32;
    int l1 = min(cnt, l0 + 32);
    if (l0 >= l1) return;
    int d4 = threadIdx.x * 4;
    float4 acc = {0.f, 0.f, 0.f, 0.f};
    for (int l = l0; l < l1; l++) {
        int p = lists[b * LMAX + l];
        const float4 vv = *(const float4*)&f2[((size_t)(b * LMAX + p)) * D + d4];
        acc.x += vv.x; acc.y += vv.y; acc.z += vv.z; acc.w += vv.w;
    }
    float inv = 1.f / (float)max(cnt, 1);
    atomicAdd(&out[(size_t)b * D + d4 + 0], acc.x * inv);
    atomicAdd(&out[(size_t)b * D + d4 + 1], acc.y * inv);
    atomicAdd(&out[(size_t)b * D + d4 + 2], acc.z * inv);
    atomicAdd(&out[(size_t)b * D + d4 + 3], acc.w * inv);
}

// ---------------------------------------------------------------------------
extern "C" void kernel_launch(void* const* d_in, const int* in_sizes, int n_in,
                              void* d_out, int out_size, void* d_ws, size_t ws_size,
                              hipStream_t stream) {
    const float* struct_token = (const float*)d_in[0];
    const float* text_token   = (const float*)d_in[1];
    const float* in_proj_w    = (const float*)d_in[2];
    const float* in_proj_b    = (const float*)d_in[3];
    const float* attn_out_w   = (const float*)d_in[4];
    const float* attn_out_b   = (const float*)d_in[5];
    const float* ln_g         = (const float*)d_in[6];
    const float* ln_b         = (const float*)d_in[7];
    const float* proj_w       = (const float*)d_in[8];
    const float* proj_b       = (const float*)d_in[9];
    const int*   sb           = (const int*)d_in[10];
    float* out = (float*)d_out;

    const size_t MQ  = (size_t)B * LMAX;     // 4096
    const size_t MKV = (size_t)B * LT;       // 8192

    char* p = (char*)d_ws;
    unsigned short* padded_b = (unsigned short*)p;  p += MQ * D * 2;
    unsigned short* text_b   = (unsigned short*)p;  p += MKV * D * 2;
    unsigned short* wqkv_b   = (unsigned short*)p;  p += (size_t)3 * D * D * 2;
    unsigned short* wattn_b  = (unsigned short*)p;  p += (size_t)D * D * 2;
    unsigned short* wproj_b  = (unsigned short*)p;  p += (size_t)D * D * 2;
    unsigned short* qb       = (unsigned short*)p;  p += MQ * D * 2;
    unsigned short* kb       = (unsigned short*)p;  p += MKV * D * 2;
    unsigned short* vtb      = (unsigned short*)p;  p += MKV * D * 2;   // [D][MKV]
    unsigned short* ctx_b    = (unsigned short*)p;  p += MQ * D * 2;
    unsigned short* f1b_b    = (unsigned short*)p;  p += MQ * D * 2;
    float* f1 = (float*)p;  p += MQ * D * 4;
    float* f2 = (float*)p;  p += MQ * D * 4;
    int* pos    = (int*)p;  p += N * 4;
    int* counts = (int*)p;  p += B * 4;
    int* starts = (int*)p;  p += B * 4;
    int* lists  = (int*)p;  p += B * LMAX * 4;

    hipMemsetAsync(padded_b, 0, MQ * D * 2, stream);
    hipMemsetAsync(out, 0, (size_t)B * D * 4, stream);
    prep_kernel<<<1, 256, 0, stream>>>(sb, counts, starts, pos, lists);
    scatter_kernel<<<N, 256, 0, stream>>>(struct_token, sb, pos, padded_b);

    cast_kernel<<<(int)(MKV * D / 8 / 256), 256, 0, stream>>>(text_token, text_b, (int)(MKV * D));
    cast_kernel<<<(int)(3 * D * D / 8 / 256), 256, 0, stream>>>(in_proj_w, wqkv_b, 3 * D * D);
    cast_kernel<<<(int)(D * D / 8 / 256), 256, 0, stream>>>(attn_out_w, wattn_b, D * D);
    cast_kernel<<<(int)(D * D / 8 / 256), 256, 0, stream>>>(proj_w, wproj_b, D * D);

    // Q, K: bf16 out. V computed TRANSPOSED (swap A/W, bias along rows) -> vtb [D][MKV].
    gemm_mfma<unsigned short, false><<<dim3(D / 128, MQ / 128), 256, 0, stream>>>(
        padded_b, wqkv_b, in_proj_b, qb, (int)MQ, D, D);
    gemm_mfma<unsigned short, false><<<dim3(D / 128, MKV / 128), 256, 0, stream>>>(
        text_b, wqkv_b + (size_t)D * D, in_proj_b + D, kb, (int)MKV, D, D);
    gemm_mfma<unsigned short, true><<<dim3(MKV / 128, D / 128), 256, 0, stream>>>(
        wqkv_b + 2 * (size_t)D * D, text_b, in_proj_b + 2 * D, vtb, D, (int)MKV, D);

    attn_mfma<<<dim3(LMAX / 64, H, B), 256, 0, stream>>>(qb, kb, vtb, ctx_b);

    gemm_mfma<float, false><<<dim3(D / 128, MQ / 128), 256, 0, stream>>>(
        ctx_b, wattn_b, attn_out_b, f1, (int)MQ, D, D);
    ln_kernel<<<(int)MQ, 256, 0, stream>>>(f1, f1b_b, ln_g, ln_b);

    gemm_mfma<float, false><<<dim3(D / 128, MQ / 128), 256, 0, stream>>>(
        f1b_b, wproj_b, proj_b, f2, (int)MQ, D, D);

    mean_kernel<<<dim3(B, LMAX / 32), 256, 0, stream>>>(f2, counts, lists, out);
}

// Round 4
// 306.772 us; speedup vs baseline: 4.8489x; 1.1137x over previous
//
#include <hip/hip_runtime.h>

// Problem constants
constexpr int B  = 16;
constexpr int LT = 512;
constexpr int D  = 1024;
constexpr int N  = 4096;
constexpr int H  = 16;
constexpr int DH = D / H;       // 64
constexpr int LMAX = N / B;     // 256
constexpr float LN_EPS = 1e-5f;

typedef short  s16x8 __attribute__((ext_vector_type(8)));
typedef float  f32x4 __attribute__((ext_vector_type(4)));

__device__ __forceinline__ unsigned short f2bf(float x) {
    unsigned int u = __float_as_uint(x);
    unsigned int r = (u + 0x7fffu + ((u >> 16) & 1u)) >> 16;   // RNE
    return (unsigned short)r;
}

__device__ __forceinline__ void load_lds16(const void* g, void* l) {
    __builtin_amdgcn_global_load_lds(
        (const __attribute__((address_space(1))) unsigned int*)g,
        (__attribute__((address_space(3))) unsigned int*)l, 16, 0, 0);
}

// ---------------------------------------------------------------------------
__global__ void prep_kernel(const int* __restrict__ sb, int* __restrict__ counts,
                            int* __restrict__ starts, int* __restrict__ pos) {
    __shared__ int s_counts[B], s_starts[B];
    int t = threadIdx.x;
    if (t < B) s_counts[t] = 0;
    __syncthreads();
    for (int i = t; i < N; i += 256) atomicAdd(&s_counts[sb[i]], 1);
    __syncthreads();
    if (t == 0) {
        int run = 0;
        for (int b = 0; b < B; b++) { s_starts[b] = run; run += s_counts[b]; }
    }
    __syncthreads();
    if (t < B) { counts[t] = s_counts[t]; starts[t] = s_starts[t]; }
    for (int i = t; i < N; i += 256) {
        int b = sb[i];
        pos[i] = i - s_starts[b];
    }
}

// ---------------------------------------------------------------------------
__global__ void scatter_kernel(const float* __restrict__ st, const int* __restrict__ sb,
                               const int* __restrict__ pos, unsigned short* __restrict__ padded) {
    int i = blockIdx.x;
    int b = sb[i], p = pos[i];
    int d = threadIdx.x * 4;
    float4 v = *(const float4*)&st[(size_t)i * D + d];
    ushort4 o;
    o.x = f2bf(v.x); o.y = f2bf(v.y); o.z = f2bf(v.z); o.w = f2bf(v.w);
    *(ushort4*)&padded[((size_t)(b * LMAX + p)) * D + d] = o;
}

// fused fp32->bf16 cast of three regions (8 elems/thread; each n % 8 == 0)
__global__ __launch_bounds__(256) void cast3_kernel(
        const float* __restrict__ x0, unsigned short* __restrict__ y0, int n0,
        const float* __restrict__ x1, unsigned short* __restrict__ y1, int n1,
        const float* __restrict__ x2, unsigned short* __restrict__ y2, int n2) {
    long long i = (long long)(blockIdx.x * 256 + threadIdx.x) * 8;
    const float* x; unsigned short* y;
    if (i < n0)                { x = x0 + i; y = y0 + i; }
    else if (i < (long long)n0 + n1) { long long j = i - n0; x = x1 + j; y = y1 + j; }
    else if (i < (long long)n0 + n1 + n2) { long long j = i - n0 - n1; x = x2 + j; y = y2 + j; }
    else return;
    float4 a = *(const float4*)x;
    float4 b = *(const float4*)(x + 4);
    ushort4 o1, o2;
    o1.x = f2bf(a.x); o1.y = f2bf(a.y); o1.z = f2bf(a.z); o1.w = f2bf(a.w);
    o2.x = f2bf(b.x); o2.y = f2bf(b.y); o2.z = f2bf(b.z); o2.w = f2bf(b.w);
    *(ushort4*)y = o1;
    *(ushort4*)(y + 4) = o2;
}

// ---------------------------------------------------------------------------
// GEMM tile body: C[m0:+128, n0:+128] = A @ W^T + bias. A,W bf16. 256 threads.
template<typename OutT, bool BIAS_ROW>
__device__ __forceinline__ void gemm_tile(const unsigned short* __restrict__ A,
                                          const unsigned short* __restrict__ W,
                                          const float* __restrict__ bias,
                                          OutT* __restrict__ C,
                                          int Nn, int K, int m0, int n0,
                                          unsigned short* As, unsigned short* Bs) {
    const int tid  = threadIdx.x;
    const int lane = tid & 63;
    const int wave = tid >> 6;
    const int wm = (wave >> 1) * 64, wn = (wave & 1) * 64;

    const int srow = tid >> 2;
    const int scol = (tid & 3) * 8;
    const unsigned short* Ag = A + (size_t)(m0 + srow) * K + scol;
    const unsigned short* Wg = W + (size_t)(n0 + srow) * K + scol;
    unsigned short* Asl = As + tid * 8;
    unsigned short* Bsl = Bs + tid * 8;

    const int fm = lane & 15;
    const int fk = (lane >> 4) * 8;

    f32x4 acc[4][4];
#pragma unroll
    for (int i = 0; i < 4; i++)
#pragma unroll
        for (int j = 0; j < 4; j++) acc[i][j] = (f32x4){0.f, 0.f, 0.f, 0.f};

    for (int k0 = 0; k0 < K; k0 += 32) {
        __syncthreads();
        load_lds16(Ag + k0, Asl);
        load_lds16(Ag + (size_t)64 * K + k0, Asl + 64 * 32);
        load_lds16(Wg + k0, Bsl);
        load_lds16(Wg + (size_t)64 * K + k0, Bsl + 64 * 32);
        __syncthreads();

        s16x8 af[4], bf[4];
#pragma unroll
        for (int i = 0; i < 4; i++) {
            af[i] = *(const s16x8*)&As[(wm + i * 16 + fm) * 32 + fk];
            bf[i] = *(const s16x8*)&Bs[(wn + i * 16 + fm) * 32 + fk];
        }
#pragma unroll
        for (int i = 0; i < 4; i++)
#pragma unroll
            for (int j = 0; j < 4; j++)
                acc[i][j] = __builtin_amdgcn_mfma_f32_16x16x32_bf16(af[i], bf[j], acc[i][j], 0, 0, 0);
    }

    const int fr = (lane >> 4) * 4;
#pragma unroll
    for (int j = 0; j < 4; j++) {
        int col = n0 + wn + j * 16 + fm;
        float bc = BIAS_ROW ? 0.f : bias[col];
#pragma unroll
        for (int i = 0; i < 4; i++) {
            size_t rbase = (size_t)(m0 + wm + i * 16 + fr) * Nn + col;
#pragma unroll
            for (int r = 0; r < 4; r++) {
                float val = acc[i][j][r] + (BIAS_ROW ? bias[m0 + wm + i * 16 + fr + r] : bc);
                if constexpr (sizeof(OutT) == 2)
                    C[rbase + (size_t)r * Nn] = (OutT)f2bf(val);
                else
                    C[rbase + (size_t)r * Nn] = (OutT)val;
            }
        }
    }
}

// Fused QKV: flat grid of 1280 blocks. [0,256)=Q, [256,768)=K, [768,1280)=V^T.
__global__ __launch_bounds__(256) void qkv_fused(const unsigned short* __restrict__ padded,
                                                 const unsigned short* __restrict__ text,
                                                 const unsigned short* __restrict__ wqkv,
                                                 const float* __restrict__ bqkv,
                                                 unsigned short* __restrict__ qb,
                                                 unsigned short* __restrict__ kb,
                                                 unsigned short* __restrict__ vtb) {
    __shared__ __align__(16) unsigned short As[128 * 32];
    __shared__ __align__(16) unsigned short Bs[128 * 32];
    int flat = blockIdx.x;
    if (flat < 256) {
        gemm_tile<unsigned short, false>(padded, wqkv, bqkv, qb,
                                         D, D, (flat >> 3) * 128, (flat & 7) * 128, As, Bs);
    } else if (flat < 768) {
        int f = flat - 256;
        gemm_tile<unsigned short, false>(text, wqkv + (size_t)D * D, bqkv + D, kb,
                                         D, D, (f >> 3) * 128, (f & 7) * 128, As, Bs);
    } else {
        int f = flat - 768;   // V^T: A=wv rows (M=1024), W=text (Nn=8192), bias by row
        gemm_tile<unsigned short, true>(wqkv + 2 * (size_t)D * D, text, bqkv + 2 * D, vtb,
                                        B * LT, D, (f >> 6) * 128, (f & 63) * 128, As, Bs);
    }
}

// Standalone GEMM (attn_out), fp32 out
__global__ __launch_bounds__(256) void gemm_f32(const unsigned short* __restrict__ A,
                                                const unsigned short* __restrict__ W,
                                                const float* __restrict__ bias,
                                                float* __restrict__ C, int Nn, int K) {
    __shared__ __align__(16) unsigned short As[128 * 32];
    __shared__ __align__(16) unsigned short Bs[128 * 32];
    gemm_tile<float, false>(A, W, bias, C, Nn, K,
                            blockIdx.y * 128, blockIdx.x * 128, As, Bs);
}

// ---------------------------------------------------------------------------
// MFMA attention (unchanged from round 3)
__global__ __launch_bounds__(256) void attn_mfma(const unsigned short* __restrict__ qb,
                                                 const unsigned short* __restrict__ kb,
                                                 const unsigned short* __restrict__ vtb,
                                                 unsigned short* __restrict__ ctx) {
    __shared__ __align__(16) unsigned short KV[128 * 72];
    __shared__ __align__(16) unsigned short Ps[4 * 16 * 136];

    const int tid = threadIdx.x;
    const int lane = tid & 63;
    const int wv = tid >> 6;
    const int fm = lane & 15;
    const int quad = lane >> 4;
    const int b = blockIdx.z, h = blockIdx.y;
    const int q0 = blockIdx.x * 64 + wv * 16;

    const size_t qrow = (size_t)(b * LMAX + q0 + fm) * D + h * DH;
    const s16x8 aq0 = *(const s16x8*)&qb[qrow + quad * 8];
    const s16x8 aq1 = *(const s16x8*)&qb[qrow + 32 + quad * 8];

    f32x4 sc[32];
#pragma unroll
    for (int t = 0; t < 32; t++) sc[t] = (f32x4){0.f, 0.f, 0.f, 0.f};

    const size_t kbase = (size_t)(b * LT) * D + h * DH;
    for (int c = 0; c < 4; c++) {
        __syncthreads();
#pragma unroll
        for (int it = 0; it < 4; it++) {
            int e = it * 2048 + tid * 8;
            int row = e >> 6, col = e & 63;
            *(s16x8*)&KV[row * 72 + col] =
                *(const s16x8*)&kb[kbase + (size_t)(c * 128 + row) * D + col];
        }
        __syncthreads();
#pragma unroll
        for (int t = 0; t < 8; t++) {
            s16x8 bk0 = *(const s16x8*)&KV[(t * 16 + fm) * 72 + quad * 8];
            s16x8 bk1 = *(const s16x8*)&KV[(t * 16 + fm) * 72 + 32 + quad * 8];
            f32x4 a = sc[c * 8 + t];
            a = __builtin_amdgcn_mfma_f32_16x16x32_bf16(aq0, bk0, a, 0, 0, 0);
            a = __builtin_amdgcn_mfma_f32_16x16x32_bf16(aq1, bk1, a, 0, 0, 0);
            sc[c * 8 + t] = a;
        }
    }

    const float scale = 0.125f;
    float mx[4], l[4], inv[4];
#pragma unroll
    for (int r = 0; r < 4; r++) {
        float m = sc[0][r];
#pragma unroll
        for (int t = 1; t < 32; t++) m = fmaxf(m, sc[t][r]);
        mx[r] = m;
    }
#pragma unroll
    for (int o = 1; o < 16; o <<= 1)
#pragma unroll
        for (int r = 0; r < 4; r++) mx[r] = fmaxf(mx[r], __shfl_xor(mx[r], o));
#pragma unroll
    for (int r = 0; r < 4; r++) l[r] = 0.f;
#pragma unroll
    for (int t = 0; t < 32; t++)
#pragma unroll
        for (int r = 0; r < 4; r++) {
            float e = __expf((sc[t][r] - mx[r]) * scale);
            sc[t][r] = e;
            l[r] += e;
        }
#pragma unroll
    for (int o = 1; o < 16; o <<= 1)
#pragma unroll
        for (int r = 0; r < 4; r++) l[r] += __shfl_xor(l[r], o);
#pragma unroll
    for (int r = 0; r < 4; r++) inv[r] = 1.f / l[r];

    f32x4 co[4];
#pragma unroll
    for (int n = 0; n < 4; n++) co[n] = (f32x4){0.f, 0.f, 0.f, 0.f};
    unsigned short* Pw = Ps + wv * (16 * 136);
    const size_t vbase = (size_t)(h * DH) * (B * LT) + (size_t)b * LT;

    for (int c = 0; c < 4; c++) {
        __syncthreads();
#pragma unroll
        for (int it = 0; it < 4; it++) {
            int e = it * 2048 + tid * 8;
            int row = e >> 7, col = e & 127;
            *(s16x8*)&KV[row * 136 + col] =
                *(const s16x8*)&vtb[vbase + (size_t)row * (B * LT) + c * 128 + col];
        }
#pragma unroll
        for (int t = 0; t < 8; t++)
#pragma unroll
            for (int r = 0; r < 4; r++)
                Pw[(quad * 4 + r) * 136 + t * 16 + fm] = f2bf(sc[c * 8 + t][r]);
        __syncthreads();
#pragma unroll
        for (int s = 0; s < 4; s++) {
            s16x8 ap = *(const s16x8*)&Pw[fm * 136 + s * 32 + quad * 8];
#pragma unroll
            for (int n = 0; n < 4; n++) {
                s16x8 bv = *(const s16x8*)&KV[(n * 16 + fm) * 136 + s * 32 + quad * 8];
                co[n] = __builtin_amdgcn_mfma_f32_16x16x32_bf16(ap, bv, co[n], 0, 0, 0);
            }
        }
    }

    const size_t obase = (size_t)(b * LMAX + q0) * D + h * DH;
#pragma unroll
    for (int n = 0; n < 4; n++)
#pragma unroll
        for (int r = 0; r < 4; r++)
            ctx[obase + (size_t)(quad * 4 + r) * D + n * 16 + fm] = f2bf(co[n][r] * inv[r]);
}

// ---------------------------------------------------------------------------
// Fused LayerNorm + segment-mean partial: block = (batch b, group of 32 slots).
// For each real row: LN it, accumulate into acc; atomicAdd acc/cnt into msum[b].
__global__ __launch_bounds__(256) void lnmean_kernel(const float* __restrict__ f1,
                                                     const float* __restrict__ g,
                                                     const float* __restrict__ bb,
                                                     const int* __restrict__ counts,
                                                     float* __restrict__ msum) {
    int b = blockIdx.x;
    int cnt = counts[b];
    int s0 = blockIdx.y * 32;
    int s1 = min(cnt, s0 + 32);
    if (s0 >= s1) return;
    int t = threadIdx.x;
    int wv = t >> 6, ln = t & 63;
    float4 gg = ((const float4*)g)[t];
    float4 bv = ((const float4*)bb)[t];
    float acc[4] = {0.f, 0.f, 0.f, 0.f};
    __shared__ float red[8];

    for (int s = s0; s < s1; s++) {
        const float* x = f1 + ((size_t)(b * LMAX + s)) * D;
        float4 val = ((const float4*)x)[t];
        float sm = val.x + val.y + val.z + val.w;
        float ss = val.x * val.x + val.y * val.y + val.z * val.z + val.w * val.w;
#pragma unroll
        for (int o = 32; o; o >>= 1) { sm += __shfl_xor(sm, o); ss += __shfl_xor(ss, o); }
        if (ln == 0) { red[wv] = sm; red[4 + wv] = ss; }
        __syncthreads();
        sm = red[0] + red[1] + red[2] + red[3];
        ss = red[4] + red[5] + red[6] + red[7];
        __syncthreads();
        float mu = sm * (1.f / D);
        float var = ss * (1.f / D) - mu * mu;
        float r = rsqrtf(var + LN_EPS);
        acc[0] += (val.x - mu) * r * gg.x + bv.x;
        acc[1] += (val.y - mu) * r * gg.y + bv.y;
        acc[2] += (val.z - mu) * r * gg.z + bv.z;
        acc[3] += (val.w - mu) * r * gg.w + bv.w;
    }
    float inv = 1.f / (float)max(cnt, 1);
#pragma unroll
    for (int j = 0; j < 4; j++)
        atomicAdd(&msum[(size_t)b * D + t * 4 + j], acc[j] * inv);
}

// Mini projection: out[b][n] = msum[b] . proj_w[n] + bias[n]  (all fp32).
// One wave per output column n; grid 256 blocks x 4 waves.
__global__ __launch_bounds__(256) void tproj_kernel(const float* __restrict__ msum,
                                                    const float* __restrict__ W,
                                                    const float* __restrict__ bias,
                                                    float* __restrict__ out) {
    int lane = threadIdx.x & 63;
    int n = blockIdx.x * 4 + (threadIdx.x >> 6);
    float4 wr[4];
#pragma unroll
    for (int i = 0; i < 4; i++)
        wr[i] = *(const float4*)&W[(size_t)n * D + i * 256 + lane * 4];
    float bn = bias[n];
    for (int b = 0; b < B; b++) {
        float s = 0.f;
#pragma unroll
        for (int i = 0; i < 4; i++) {
            float4 m4 = *(const float4*)&msum[(size_t)b * D + i * 256 + lane * 4];
            s += m4.x * wr[i].x + m4.y * wr[i].y + m4.z * wr[i].z + m4.w * wr[i].w;
        }
#pragma unroll
        for (int o = 32; o; o >>= 1) s += __shfl_xor(s, o);
        if (lane == 0) out[(size_t)b * D + n] = s + bn;
    }
}

// ---------------------------------------------------------------------------
extern "C" void kernel_launch(void* const* d_in, const int* in_sizes, int n_in,
                              void* d_out, int out_size, void* d_ws, size_t ws_size,
                              hipStream_t stream) {
    const float* struct_token = (const float*)d_in[0];
    const float* text_token   = (const float*)d_in[1];
    const float* in_proj_w    = (const float*)d_in[2];
    const float* in_proj_b    = (const float*)d_in[3];
    const float* attn_out_w   = (const float*)d_in[4];
    const float* attn_out_b   = (const float*)d_in[5];
    const float* ln_g         = (const float*)d_in[6];
    const float* ln_b         = (const float*)d_in[7];
    const float* proj_w       = (const float*)d_in[8];
    const float* proj_b       = (const float*)d_in[9];
    const int*   sb           = (const int*)d_in[10];
    float* out = (float*)d_out;

    const size_t MQ  = (size_t)B * LMAX;     // 4096
    const size_t MKV = (size_t)B * LT;       // 8192

    char* p = (char*)d_ws;
    unsigned short* padded_b = (unsigned short*)p;  p += MQ * D * 2;
    unsigned short* text_b   = (unsigned short*)p;  p += MKV * D * 2;
    unsigned short* wqkv_b   = (unsigned short*)p;  p += (size_t)3 * D * D * 2;
    unsigned short* wattn_b  = (unsigned short*)p;  p += (size_t)D * D * 2;
    unsigned short* qb       = (unsigned short*)p;  p += MQ * D * 2;
    unsigned short* kb       = (unsigned short*)p;  p += MKV * D * 2;
    unsigned short* vtb      = (unsigned short*)p;  p += MKV * D * 2;   // [D][MKV]
    unsigned short* ctx_b    = (unsigned short*)p;  p += MQ * D * 2;
    float* f1   = (float*)p;  p += MQ * D * 4;
    float* msum = (float*)p;  p += (size_t)B * D * 4;
    int* pos    = (int*)p;  p += N * 4;
    int* counts = (int*)p;  p += B * 4;
    int* starts = (int*)p;  p += B * 4;

    hipMemsetAsync(padded_b, 0, MQ * D * 2, stream);
    hipMemsetAsync(msum, 0, (size_t)B * D * 4, stream);
    prep_kernel<<<1, 256, 0, stream>>>(sb, counts, starts, pos);
    scatter_kernel<<<N, 256, 0, stream>>>(struct_token, sb, pos, padded_b);

    // casts: text (8.4M), wqkv (3.1M), wattn (1.0M) -> 12.58M elems, 6144 blocks
    cast3_kernel<<<6144, 256, 0, stream>>>(
        text_token, text_b, (int)(MKV * D),
        in_proj_w,  wqkv_b, 3 * D * D,
        attn_out_w, wattn_b, D * D);

    // fused Q + K + V^T (1280 blocks)
    qkv_fused<<<1280, 256, 0, stream>>>(padded_b, text_b, wqkv_b, in_proj_b, qb, kb, vtb);

    attn_mfma<<<dim3(LMAX / 64, H, B), 256, 0, stream>>>(qb, kb, vtb, ctx_b);

    // attn_out projection -> f1 (fp32)
    gemm_f32<<<dim3(D / 128, MQ / 128), 256, 0, stream>>>(ctx_b, wattn_b, attn_out_b, f1, D, D);

    // fused LN + segment-mean -> msum (fp32 partials)
    lnmean_kernel<<<dim3(B, LMAX / 32), 256, 0, stream>>>(f1, ln_g, ln_b, counts, msum);

    // mini projection (fp32): out = msum @ proj_w^T + proj_b
    tproj_kernel<<<256, 256, 0, stream>>>(msum, proj_w, proj_b, out);
}